// Round 2
// baseline (437.758 us; speedup 1.0000x reference)
//
#include <hip/hip_runtime.h>

#define IN_F 512
#define HID_F 256
#define LAT_F 128

typedef __bf16 bf16x8 __attribute__((ext_vector_type(8)));
typedef float floatx4 __attribute__((ext_vector_type(4)));

#define FIX_SCALE 1048576.0f   // 2^20 fixed-point for degree accumulation

__device__ __forceinline__ unsigned short f2bf(float f) {
    union { float f; unsigned u; } v; v.f = f;
    unsigned r = (v.u + 0x7fff + ((v.u >> 16) & 1)) >> 16;
    return (unsigned short)r;
}
__device__ __forceinline__ float bf2f(unsigned short h) {
    union { unsigned u; float f; } v; v.u = ((unsigned)h) << 16;
    return v.f;
}

// async 16B global -> LDS DMA (dest = wave-uniform base + lane*16)
__device__ __forceinline__ void gload_lds16(const void* g, void* lds) {
    __builtin_amdgcn_global_load_lds(
        (const __attribute__((address_space(1))) unsigned int*)(uintptr_t)g,
        (__attribute__((address_space(3))) unsigned int*)(uintptr_t)lds,
        16, 0, 0);
}

// ---------------- fused prep: packed init + weight transpose/bf16 ----------------

__global__ void prep_all(const float* __restrict__ W1, const float* __restrict__ Wmu,
                         const float* __restrict__ Wlv, unsigned long long* __restrict__ packed,
                         unsigned short* __restrict__ W1t, unsigned short* __restrict__ B2t,
                         int N) {
    int t = blockIdx.x * 256 + threadIdx.x;
    if (t < N) packed[t] = (1ULL << 32) | (unsigned long long)(unsigned)FIX_SCALE;  // count=1, w=1.0
    if (t < HID_F * IN_F) {            // W1t[n][k] = bf16(W1[k][n])
        int n = t >> 9, k = t & 511;
        W1t[t] = f2bf(W1[(size_t)k * HID_F + n]);
    }
    if (t < HID_F * HID_F) {           // B2t[n][k] = bf16([Wmu|Wlv][k][n])
        int n = t >> 8, k = t & 255;
        float v = (n < 128) ? Wmu[(size_t)k * LAT_F + n] : Wlv[(size_t)k * LAT_F + (n - 128)];
        B2t[t] = f2bf(v);
    }
}

// ---------------- degree pass: ONE u64 atomic per edge; returns CSR slot ----------------

__global__ void edge_deg(const int* __restrict__ ei, const float* __restrict__ attr,
                         unsigned long long* __restrict__ packed, int* __restrict__ slot, int E) {
    int e = blockIdx.x * 256 + threadIdx.x;
    if (e < E) {
        int d = ei[E + e];
        unsigned fw = __float2uint_rn(attr[e] * FIX_SCALE);
        unsigned long long old = atomicAdd(&packed[d], (1ULL << 32) | (unsigned long long)fw);
        slot[e] = (int)(old >> 32);    // count before increment (self-loop holds slot 0)
    }
}

// ---------------- scan pass 1 (fused with dis computation) ----------------

__global__ void scan_blocks(const unsigned long long* __restrict__ packed,
                            float* __restrict__ dis, int* __restrict__ excl,
                            int* __restrict__ blockSums, int N) {
    __shared__ int sdata[256];
    int tid = threadIdx.x;
    int base = blockIdx.x * 1024 + tid * 4;
    int v[4]; int sum = 0;
#pragma unroll
    for (int j = 0; j < 4; ++j) {
        int c = 0;
        if (base + j < N) {
            unsigned long long p = packed[base + j];
            c = (int)(p >> 32);
            float dg = (float)(unsigned)(p & 0xffffffffu) * (1.0f / FIX_SCALE);
            dis[base + j] = dg > 0.f ? rsqrtf(fmaxf(dg, 1e-12f)) : 0.f;
        }
        v[j] = c; sum += c;
    }
    sdata[tid] = sum;
    __syncthreads();
    for (int off = 1; off < 256; off <<= 1) {
        int t = (tid >= off) ? sdata[tid - off] : 0;
        __syncthreads();
        sdata[tid] += t;
        __syncthreads();
    }
    if (tid == 255) blockSums[blockIdx.x] = sdata[255];
    int run = sdata[tid] - sum;
#pragma unroll
    for (int j = 0; j < 4; ++j) { if (base + j < N) excl[base + j] = run; run += v[j]; }
}

__global__ void scan_sums(int* blockSums, int NB) {
    __shared__ int s[64];
    int tid = threadIdx.x;
    int v = (tid < NB) ? blockSums[tid] : 0;
    s[tid] = v;
    __syncthreads();
    for (int off = 1; off < 64; off <<= 1) {
        int t = (tid >= off) ? s[tid - off] : 0;
        __syncthreads();
        s[tid] += t;
        __syncthreads();
    }
    if (tid < NB) blockSums[tid] = s[tid] - v;
}

__global__ void scan_add(int* row_ptr, const int* __restrict__ blockSums, int N, int total) {
    int tid = threadIdx.x;
    int base = blockIdx.x * 1024 + tid * 4;
    int add = blockSums[blockIdx.x];
#pragma unroll
    for (int j = 0; j < 4; ++j) if (base + j < N) row_ptr[base + j] += add;
    if (blockIdx.x == 0 && tid == 0) row_ptr[N] = total;
}

// ---------------- CSR fill (NO atomics — slots precomputed) ----------------

__global__ void fill_csr(const int* __restrict__ ei, const float* __restrict__ attr,
                         const int* __restrict__ slot, const float* __restrict__ dis,
                         const int* __restrict__ row_ptr,
                         int* __restrict__ col, float* __restrict__ val, int E, int N) {
    int e = blockIdx.x * 256 + threadIdx.x;
    if (e >= E + N) return;
    int s, d, sl; float w;
    if (e < E) { s = ei[e]; d = ei[E + e]; w = attr[e]; sl = slot[e]; }
    else       { s = d = e - E; w = 1.0f; sl = 0; }
    int pos = row_ptr[d] + sl;
    col[pos] = s;
    val[pos] = dis[s] * w * dis[d];
}

// ---------------- MFMA bf16 GEMM, software-pipelined (1 barrier / k-step) ----------------
// C[M,256] = A[M,K] @ Bt[256,K]^T, C bf16. BM=32, BN=256, BK=32; 4 waves;
// wave w owns 32 rows x cols [64w,64w+64) as a 2x4 grid of 16x16x32 MFMA tiles.
// BM=32 (was 64): grid 1563 blocks (6.1/CU demanded), LDS 36KB -> 4 blocks/CU,
// occupancy ~50% vs 20% — cross-block overlap fills the per-step barrier-drain stalls.

template <bool ABF16>
__global__ __launch_bounds__(256) void gemm_mfma(const void* __restrict__ Avoid,
                                                 const unsigned short* __restrict__ Bt,
                                                 unsigned short* __restrict__ C,
                                                 int M, int K) {
    __shared__ unsigned short As[2][32 * 32];    // 2 x 2 KB
    __shared__ unsigned short Bs[2][256 * 32];   // 2 x 16 KB
    int tid = threadIdx.x;
    int wave = tid >> 6, lane = tid & 63;
    int mrow = lane & 15, quad = lane >> 4;
    int blockRow = blockIdx.x * 32;

    const unsigned short* Abf = (const unsigned short*)Avoid;
    const float*          Afp = (const float*)Avoid;

    floatx4 acc[2][4];
#pragma unroll
    for (int i = 0; i < 2; ++i)
#pragma unroll
        for (int j = 0; j < 4; ++j) acc[i][j] = (floatx4){0.f, 0.f, 0.f, 0.f};

    int r = tid >> 2;            // 0..63 : B col-mod-64; A row for tid<128
    int kq = tid & 3;            // 16B chunk within the 32-halfword k-slab
    bool astage = tid < 128;     // waves 0,1 stage A (32 rows x 32 hw = 2 KB)
    int arow = blockRow + (r & 31); if (arow >= M) arow = M - 1;  // clamp (tail discarded at store)

    // ---- prologue: stage k=0 into buffer 0 ----
    if constexpr (ABF16) {
        if (astage) gload_lds16(Abf + (size_t)arow * K + kq * 8, &As[0][wave * 512]);
    } else {
        if (astage) {
            const float* p = Afp + (size_t)arow * K + kq * 8;
            float4 a0 = *(const float4*)p, a1 = *(const float4*)(p + 4);
            unsigned short h[8] = {f2bf(a0.x), f2bf(a0.y), f2bf(a0.z), f2bf(a0.w),
                                   f2bf(a1.x), f2bf(a1.y), f2bf(a1.z), f2bf(a1.w)};
            *(uint4*)&As[0][r * 32 + kq * 8] = *(uint4*)h;
        }
    }
#pragma unroll
    for (int pass = 0; pass < 4; ++pass)
        gload_lds16(Bt + (size_t)(r + pass * 64) * K + kq * 8,
                    &Bs[0][(pass * 256 + wave * 64) * 8]);

    int cur = 0;
    for (int k0 = 0; k0 < K; k0 += 32) {
        __syncthreads();   // drains prev-iteration prefetch: buf[cur] is ready
        int kn = k0 + 32;
        bool more = kn < K;
        float4 a0, a1;
        if (more) {
            if constexpr (ABF16) {
                if (astage) gload_lds16(Abf + (size_t)arow * K + kn + kq * 8, &As[cur ^ 1][wave * 512]);
            } else {
                if (astage) {
                    const float* p = Afp + (size_t)arow * K + kn + kq * 8;
                    a0 = *(const float4*)p; a1 = *(const float4*)(p + 4);
                }
            }
#pragma unroll
            for (int pass = 0; pass < 4; ++pass)
                gload_lds16(Bt + (size_t)(r + pass * 64) * K + kn + kq * 8,
                            &Bs[cur ^ 1][(pass * 256 + wave * 64) * 8]);
        }
        // ---- compute on buf[cur]: 2 a-frags x 4 b-frags ----
        bf16x8 af[2];
#pragma unroll
        for (int i = 0; i < 2; ++i)
            af[i] = *(const bf16x8*)&As[cur][(i * 16 + mrow) * 32 + quad * 8];
#pragma unroll
        for (int j = 0; j < 4; ++j) {
            bf16x8 bf = *(const bf16x8*)&Bs[cur][(wave * 64 + j * 16 + mrow) * 32 + quad * 8];
#pragma unroll
            for (int i = 0; i < 2; ++i)
                acc[i][j] = __builtin_amdgcn_mfma_f32_16x16x32_bf16(af[i], bf, acc[i][j], 0, 0, 0);
        }
        if (!ABF16 && more) {  // convert + stage next A after compute (load latency overlapped)
            if (astage) {
                unsigned short h[8] = {f2bf(a0.x), f2bf(a0.y), f2bf(a0.z), f2bf(a0.w),
                                       f2bf(a1.x), f2bf(a1.y), f2bf(a1.z), f2bf(a1.w)};
                *(uint4*)&As[cur ^ 1][r * 32 + kq * 8] = *(uint4*)h;
            }
        }
        cur ^= 1;
    }
    // ---- epilogue: C/D layout col=lane&15, row=quad*4+v ----
#pragma unroll
    for (int i = 0; i < 2; ++i)
#pragma unroll
        for (int j = 0; j < 4; ++j) {
            int colo = wave * 64 + j * 16 + mrow;
#pragma unroll
            for (int v = 0; v < 4; ++v) {
                int row = blockRow + i * 16 + quad * 4 + v;
                if (row < M) C[(size_t)row * HID_F + colo] = f2bf(acc[i][j][v]);
            }
        }
}

// ---------------- aggregation (gather, CSR), bf16 m, fp32 accumulate ----------------
// Batch-8 software pipeline: load 8 (col,val) pairs (tail-clamped, zero-weight),
// then issue all 8 row-gathers before any FMA -> MLP 8 instead of 1.

__global__ void agg_relu(const unsigned short* __restrict__ m, const int* __restrict__ row_ptr,
                         const int* __restrict__ col, const float* __restrict__ val,
                         const float* __restrict__ bias, unsigned short* __restrict__ hidden) {
    int i = blockIdx.x, l = threadIdx.x, c0 = l << 2;
    int p0 = __builtin_amdgcn_readfirstlane(row_ptr[i]);
    int p1 = __builtin_amdgcn_readfirstlane(row_ptr[i + 1]);
    float a0 = 0.f, a1 = 0.f, a2 = 0.f, a3 = 0.f;
    for (int p = p0; p < p1; p += 8) {
        int sj[8]; float wj[8];
#pragma unroll
        for (int j = 0; j < 8; ++j) {
            int q = p + j;
            bool ok = q < p1; if (!ok) q = p1 - 1;   // every row has >=1 edge (self-loop)
            sj[j] = col[q];
            wj[j] = ok ? val[q] : 0.f;
        }
        ushort4 u[8];
#pragma unroll
        for (int j = 0; j < 8; ++j)
            u[j] = *(const ushort4*)(m + (size_t)sj[j] * HID_F + c0);
#pragma unroll
        for (int j = 0; j < 8; ++j) {
            a0 = fmaf(bf2f(u[j].x), wj[j], a0);
            a1 = fmaf(bf2f(u[j].y), wj[j], a1);
            a2 = fmaf(bf2f(u[j].z), wj[j], a2);
            a3 = fmaf(bf2f(u[j].w), wj[j], a3);
        }
    }
    float4 b = *(const float4*)(bias + c0);
    a0 = fmaxf(a0 + b.x, 0.f); a1 = fmaxf(a1 + b.y, 0.f);
    a2 = fmaxf(a2 + b.z, 0.f); a3 = fmaxf(a3 + b.w, 0.f);
    ushort4 o = make_ushort4(f2bf(a0), f2bf(a1), f2bf(a2), f2bf(a3));
    *(ushort4*)(hidden + (size_t)i * HID_F + c0) = o;
}

__global__ void agg_out(const unsigned short* __restrict__ m, const int* __restrict__ row_ptr,
                        const int* __restrict__ col, const float* __restrict__ val,
                        const float* __restrict__ bmu, const float* __restrict__ blv,
                        float* __restrict__ out, int N) {
    int i = blockIdx.x, l = threadIdx.x, c0 = l << 2;
    int p0 = __builtin_amdgcn_readfirstlane(row_ptr[i]);
    int p1 = __builtin_amdgcn_readfirstlane(row_ptr[i + 1]);
    float a0 = 0.f, a1 = 0.f, a2 = 0.f, a3 = 0.f;
    for (int p = p0; p < p1; p += 8) {
        int sj[8]; float wj[8];
#pragma unroll
        for (int j = 0; j < 8; ++j) {
            int q = p + j;
            bool ok = q < p1; if (!ok) q = p1 - 1;
            sj[j] = col[q];
            wj[j] = ok ? val[q] : 0.f;
        }
        ushort4 u[8];
#pragma unroll
        for (int j = 0; j < 8; ++j)
            u[j] = *(const ushort4*)(m + (size_t)sj[j] * HID_F + c0);
#pragma unroll
        for (int j = 0; j < 8; ++j) {
            a0 = fmaf(bf2f(u[j].x), wj[j], a0);
            a1 = fmaf(bf2f(u[j].y), wj[j], a1);
            a2 = fmaf(bf2f(u[j].z), wj[j], a2);
            a3 = fmaf(bf2f(u[j].w), wj[j], a3);
        }
    }
    if (l < 32) {
        float4 b = *(const float4*)(bmu + c0);
        float4 o = make_float4(a0 + b.x, a1 + b.y, a2 + b.z, a3 + b.w);
        *(float4*)(out + (size_t)i * LAT_F + c0) = o;
    } else {
        int c = c0 - 128;
        float4 b = *(const float4*)(blv + c);
        float4 o = make_float4(a0 + b.x, a1 + b.y, a2 + b.z, a3 + b.w);
        *(float4*)(out + (size_t)(N + i) * LAT_F + c) = o;
    }
}

// ---------------- launch ----------------

extern "C" void kernel_launch(void* const* d_in, const int* in_sizes, int n_in,
                              void* d_out, int out_size, void* d_ws, size_t ws_size,
                              hipStream_t stream) {
    const float* x    = (const float*)d_in[0];
    const int*   ei   = (const int*)d_in[1];
    const float* attr = (const float*)d_in[2];
    const float* W1   = (const float*)d_in[3];
    const float* b1   = (const float*)d_in[4];
    const float* Wmu  = (const float*)d_in[5];
    const float* bmu  = (const float*)d_in[6];
    const float* Wlv  = (const float*)d_in[7];
    const float* blv  = (const float*)d_in[8];
    float* out = (float*)d_out;

    const int N  = in_sizes[0] / IN_F;   // 50000
    const int E  = in_sizes[2];          // 800000
    const int EN = E + N;

    char* w = (char*)d_ws;
    size_t off = 0;
    auto carve = [&](size_t bytes) -> void* {
        void* p = w + off; off += (bytes + 255) & ~(size_t)255; return p;
    };
    unsigned long long* packed = (unsigned long long*)carve((size_t)N * 8);
    float*          dis       = (float*)carve((size_t)N * 4);
    int*            row_ptr   = (int*)  carve((size_t)(N + 1) * 4);
    int*            blockSums = (int*)  carve(64 * 4);
    int*            slot      = (int*)  carve((size_t)E * 4);
    int*            col       = (int*)  carve((size_t)EN * 4);
    float*          val       = (float*)carve((size_t)EN * 4);
    unsigned short* W1t       = (unsigned short*)carve((size_t)HID_F * IN_F * 2);
    unsigned short* B2t       = (unsigned short*)carve((size_t)HID_F * HID_F * 2);
    unsigned short* m         = (unsigned short*)carve((size_t)N * HID_F * 2);  // m1, reused as m2
    unsigned short* hidden    = (unsigned short*)carve((size_t)N * HID_F * 2);

    prep_all<<<(HID_F * IN_F + 255) / 256, 256, 0, stream>>>(W1, Wmu, Wlv, packed, W1t, B2t, N);

    edge_deg<<<(E + 255) / 256, 256, 0, stream>>>(ei, attr, packed, slot, E);

    int NB = (N + 1023) / 1024;
    scan_blocks<<<NB, 256, 0, stream>>>(packed, dis, row_ptr, blockSums, N);
    scan_sums<<<1, 64, 0, stream>>>(blockSums, NB);
    scan_add<<<NB, 256, 0, stream>>>(row_ptr, blockSums, N, EN);

    fill_csr<<<(EN + 255) / 256, 256, 0, stream>>>(ei, attr, slot, dis, row_ptr, col, val, E, N);

    int gblocks = (N + 31) / 32;
    // m1 = bf16(x) @ W1   [50000,512]x[512,256] -> bf16
    gemm_mfma<false><<<gblocks, 256, 0, stream>>>(x, W1t, m, N, IN_F);
    // hidden = relu(A_hat * m1 + b1) -> bf16
    agg_relu<<<N, 64, 0, stream>>>(m, row_ptr, col, val, b1, hidden);
    // m2 = hidden @ [W_mu | W_lv]   [50000,256]x[256,256] -> bf16
    gemm_mfma<true><<<gblocks, 256, 0, stream>>>(hidden, B2t, m, N, HID_F);
    // (mu|logvar) = A_hat * m2 + (b_mu|b_lv) -> fp32 d_out
    agg_out<<<N, 64, 0, stream>>>(m, row_ptr, col, val, bmu, blv, out, N);
}

// Round 3
// 403.219 us; speedup vs baseline: 1.0857x; 1.0857x over previous
//
#include <hip/hip_runtime.h>

#define IN_F 512
#define HID_F 256
#define LAT_F 128

typedef __bf16 bf16x8 __attribute__((ext_vector_type(8)));
typedef float floatx4 __attribute__((ext_vector_type(4)));

#define FIX_SCALE 1048576.0f   // 2^20 fixed-point for degree accumulation

__device__ __forceinline__ unsigned short f2bf(float f) {
    union { float f; unsigned u; } v; v.f = f;
    unsigned r = (v.u + 0x7fff + ((v.u >> 16) & 1)) >> 16;
    return (unsigned short)r;
}
__device__ __forceinline__ float bf2f(unsigned short h) {
    union { unsigned u; float f; } v; v.u = ((unsigned)h) << 16;
    return v.f;
}

// ---------------- fused prep: packed init + B in MFMA-fragment order ----------------
// Bf layout: frag f = ((wave*NKS + ks)*2 + jj), element (lane, j):
//   Bf[(f*64 + lane)*8 + j] = W[k][n],  n = wave*32 + jj*16 + (lane&15),
//                                        k = ks*32 + (lane>>4)*8 + j
// so a wave's B operand for k-step ks / col-frag jj is one coalesced 16B load per lane.

__global__ void prep_all(const float* __restrict__ W1, const float* __restrict__ Wmu,
                         const float* __restrict__ Wlv, unsigned long long* __restrict__ packed,
                         unsigned short* __restrict__ Bf1, unsigned short* __restrict__ Bf2,
                         int N) {
    int t = blockIdx.x * 256 + threadIdx.x;
    if (t < N) packed[t] = (1ULL << 32) | (unsigned long long)(unsigned)FIX_SCALE;  // count=1, w=1.0
    if (t < HID_F * IN_F) {            // GEMM1 frags: 8 waves x 16 ks x 2 jj x 64 lanes x 8
        int j = t & 7, l = (t >> 3) & 63, jj = (t >> 9) & 1, ks = (t >> 10) & 15, w = t >> 14;
        int n = w * 32 + jj * 16 + (l & 15);
        int k = ks * 32 + (l >> 4) * 8 + j;
        Bf1[t] = f2bf(W1[(size_t)k * HID_F + n]);
    }
    if (t < HID_F * HID_F) {           // GEMM2 frags: 8 waves x 8 ks x 2 jj x 64 lanes x 8
        int j = t & 7, l = (t >> 3) & 63, jj = (t >> 9) & 1, ks = (t >> 10) & 7, w = t >> 13;
        int n = w * 32 + jj * 16 + (l & 15);
        int k = ks * 32 + (l >> 4) * 8 + j;
        float v = (n < 128) ? Wmu[(size_t)k * LAT_F + n] : Wlv[(size_t)k * LAT_F + (n - 128)];
        Bf2[t] = f2bf(v);
    }
}

// ---------------- degree pass: ONE u64 atomic per edge; returns CSR slot ----------------

__global__ void edge_deg(const int* __restrict__ ei, const float* __restrict__ attr,
                         unsigned long long* __restrict__ packed, int* __restrict__ slot, int E) {
    int e = blockIdx.x * 256 + threadIdx.x;
    if (e < E) {
        int d = ei[E + e];
        unsigned fw = __float2uint_rn(attr[e] * FIX_SCALE);
        unsigned long long old = atomicAdd(&packed[d], (1ULL << 32) | (unsigned long long)fw);
        slot[e] = (int)(old >> 32);    // count before increment (self-loop holds slot 0)
    }
}

// ---------------- scan pass 1 (fused with dis computation) ----------------

__global__ void scan_blocks(const unsigned long long* __restrict__ packed,
                            float* __restrict__ dis, int* __restrict__ excl,
                            int* __restrict__ blockSums, int N) {
    __shared__ int sdata[256];
    int tid = threadIdx.x;
    int base = blockIdx.x * 1024 + tid * 4;
    int v[4]; int sum = 0;
#pragma unroll
    for (int j = 0; j < 4; ++j) {
        int c = 0;
        if (base + j < N) {
            unsigned long long p = packed[base + j];
            c = (int)(p >> 32);
            float dg = (float)(unsigned)(p & 0xffffffffu) * (1.0f / FIX_SCALE);
            dis[base + j] = dg > 0.f ? rsqrtf(fmaxf(dg, 1e-12f)) : 0.f;
        }
        v[j] = c; sum += c;
    }
    sdata[tid] = sum;
    __syncthreads();
    for (int off = 1; off < 256; off <<= 1) {
        int t = (tid >= off) ? sdata[tid - off] : 0;
        __syncthreads();
        sdata[tid] += t;
        __syncthreads();
    }
    if (tid == 255) blockSums[blockIdx.x] = sdata[255];
    int run = sdata[tid] - sum;
#pragma unroll
    for (int j = 0; j < 4; ++j) { if (base + j < N) excl[base + j] = run; run += v[j]; }
}

__global__ void scan_sums(int* blockSums, int NB) {
    __shared__ int s[64];
    int tid = threadIdx.x;
    int v = (tid < NB) ? blockSums[tid] : 0;
    s[tid] = v;
    __syncthreads();
    for (int off = 1; off < 64; off <<= 1) {
        int t = (tid >= off) ? s[tid - off] : 0;
        __syncthreads();
        s[tid] += t;
        __syncthreads();
    }
    if (tid < NB) blockSums[tid] = s[tid] - v;
}

__global__ void scan_add(int* row_ptr, const int* __restrict__ blockSums, int N, int total) {
    int tid = threadIdx.x;
    int base = blockIdx.x * 1024 + tid * 4;
    int add = blockSums[blockIdx.x];
#pragma unroll
    for (int j = 0; j < 4; ++j) if (base + j < N) row_ptr[base + j] += add;
    if (blockIdx.x == 0 && tid == 0) row_ptr[N] = total;
}

// ---------------- CSR fill (NO atomics — slots precomputed) ----------------

__global__ void fill_csr(const int* __restrict__ ei, const float* __restrict__ attr,
                         const int* __restrict__ slot, const float* __restrict__ dis,
                         const int* __restrict__ row_ptr,
                         int* __restrict__ col, float* __restrict__ val, int E, int N) {
    int e = blockIdx.x * 256 + threadIdx.x;
    if (e >= E + N) return;
    int s, d, sl; float w;
    if (e < E) { s = ei[e]; d = ei[E + e]; w = attr[e]; sl = slot[e]; }
    else       { s = d = e - E; w = 1.0f; sl = 0; }
    int pos = row_ptr[d] + sl;
    col[pos] = s;
    val[pos] = dis[s] * w * dis[d];
}

// ---------------- B-in-registers MFMA GEMM ----------------
// C[M,256] = A[M,KK] @ B,  B held in VGPRs (fragment order from prep).
// 512 threads = 8 waves; wave w owns cols [w*32, w*32+32) (2 col-frags).
// A streamed through LDS in 128-k super-steps: 64 rows x 128 k bf16 = 16KB,
// double-buffered (32KB). Reg-staged (T14): next step's global loads issued
// before the barrier; raw s_barrier + lgkmcnt(0) only — NO vmcnt drain, so
// HBM latency hides under the compute phase. A-tile XOR-swizzled (T2):
// chunk c stored at c^(row&7), read back with same XOR -> conflict-free af reads.
// Persistent grid (256 blocks, 1/CU), each block strides over row-tiles.

template <bool ABF16, int KK>
__global__ __launch_bounds__(512, 2) void gemm_breg(const void* __restrict__ Avoid,
                                                    const unsigned short* __restrict__ Bfrag,
                                                    unsigned short* __restrict__ C,
                                                    int M, int ntiles) {
    constexpr int NKS = KK / 32;      // total 32-k MFMA steps (16 / 8)
    constexpr int S   = KK / 128;     // super-steps per tile (4 / 2)
    __shared__ unsigned short As[2][64 * 128];   // 2 x 16KB

    int tid = threadIdx.x;
    int wave = tid >> 6, lane = tid & 63;
    int mrow = lane & 15, quad = lane >> 4;

    const unsigned short* Abf = (const unsigned short*)Avoid;
    const float*          Afp = (const float*)Avoid;

    // ---- B fragments resident in registers (coalesced 16B/lane loads) ----
    bf16x8 bfr[NKS][2];
#pragma unroll
    for (int ks = 0; ks < NKS; ++ks)
#pragma unroll
        for (int jj = 0; jj < 2; ++jj)
            bfr[ks][jj] = *(const bf16x8*)(Bfrag +
                ((((size_t)wave * NKS + ks) * 2 + jj) * 64 + lane) * 8);

    // staging: thread handles chunk c of rows r0 and r0+32 (1024 chunks / 512 thr)
    int c  = tid & 15;                 // 16B chunk within 128-k slab (16 chunks/row)
    int r0 = tid >> 4;                 // 0..31
    int cs0 = (c ^ (r0 & 7)) << 3;            // swizzled ushort offset, row r0
    int cs1 = (c ^ ((r0 + 32) & 7)) << 3;     // swizzled ushort offset, row r0+32

    float4 a0, a1, a2, a3;             // fp32 staging regs (GEMM1)
    uint4  u0, u1;                     // bf16 staging regs (GEMM2)

    auto issue = [&](int t_, int s_) {
        int g0 = t_ * 64 + r0;       if (g0 >= M) g0 = M - 1;
        int g1 = t_ * 64 + r0 + 32;  if (g1 >= M) g1 = M - 1;
        if constexpr (ABF16) {
            u0 = *(const uint4*)(Abf + (size_t)g0 * KK + s_ * 128 + c * 8);
            u1 = *(const uint4*)(Abf + (size_t)g1 * KK + s_ * 128 + c * 8);
        } else {
            const float* p0 = Afp + (size_t)g0 * KK + s_ * 128 + c * 8;
            const float* p1 = Afp + (size_t)g1 * KK + s_ * 128 + c * 8;
            a0 = *(const float4*)p0; a1 = *(const float4*)(p0 + 4);
            a2 = *(const float4*)p1; a3 = *(const float4*)(p1 + 4);
        }
    };

    floatx4 acc[4][2];
#pragma unroll
    for (int i = 0; i < 4; ++i)
#pragma unroll
        for (int jj = 0; jj < 2; ++jj) acc[i][jj] = (floatx4){0.f, 0.f, 0.f, 0.f};

    int tile = blockIdx.x;
    if (tile < ntiles) issue(tile, 0);
    int cur = 0;

    for (; tile < ntiles; tile += gridDim.x) {
#pragma unroll
        for (int s = 0; s < S; ++s) {
            // ---- write staged regs into buf[cur] (swizzled) ----
            if constexpr (ABF16) {
                *(uint4*)&As[cur][r0 * 128 + cs0] = u0;
                *(uint4*)&As[cur][(r0 + 32) * 128 + cs1] = u1;
            } else {
                unsigned short h0[8] = {f2bf(a0.x), f2bf(a0.y), f2bf(a0.z), f2bf(a0.w),
                                        f2bf(a1.x), f2bf(a1.y), f2bf(a1.z), f2bf(a1.w)};
                unsigned short h1[8] = {f2bf(a2.x), f2bf(a2.y), f2bf(a2.z), f2bf(a2.w),
                                        f2bf(a3.x), f2bf(a3.y), f2bf(a3.z), f2bf(a3.w)};
                *(uint4*)&As[cur][r0 * 128 + cs0] = *(uint4*)h0;
                *(uint4*)&As[cur][(r0 + 32) * 128 + cs1] = *(uint4*)h1;
            }
            // ---- issue next step's global loads (stay in flight across barrier) ----
            if (s + 1 < S) issue(tile, s + 1);
            else if (tile + (int)gridDim.x < ntiles) issue(tile + gridDim.x, 0);

            asm volatile("s_waitcnt lgkmcnt(0)" ::: "memory");  // my ds_writes done
            __builtin_amdgcn_s_barrier();                       // all waves' writes visible

            // ---- compute: 4 k-steps x 4 row-frags x 2 col-frags ----
#pragma unroll
            for (int ks = 0; ks < 4; ++ks) {
#pragma unroll
                for (int i = 0; i < 4; ++i) {
                    int row = i * 16 + mrow;
                    bf16x8 af = *(const bf16x8*)&As[cur][row * 128 +
                                    (((ks * 4 + quad) ^ (row & 7)) << 3)];
#pragma unroll
                    for (int jj = 0; jj < 2; ++jj)
                        acc[i][jj] = __builtin_amdgcn_mfma_f32_16x16x32_bf16(
                            af, bfr[s * 4 + ks][jj], acc[i][jj], 0, 0, 0);
                }
            }
            asm volatile("s_waitcnt lgkmcnt(0)" ::: "memory");  // reads of buf[cur] retired
            __builtin_amdgcn_s_barrier();                       // safe to overwrite next-next step
            cur ^= 1;
        }
        // ---- epilogue: C/D layout col=lane&15, row=quad*4+v ----
#pragma unroll
        for (int i = 0; i < 4; ++i)
#pragma unroll
            for (int jj = 0; jj < 2; ++jj) {
                int colo = wave * 32 + jj * 16 + mrow;
#pragma unroll
                for (int v = 0; v < 4; ++v) {
                    int row = tile * 64 + i * 16 + quad * 4 + v;
                    if (row < M) C[(size_t)row * HID_F + colo] = f2bf(acc[i][jj][v]);
                }
                acc[i][jj] = (floatx4){0.f, 0.f, 0.f, 0.f};
            }
    }
}

// ---------------- aggregation (gather, CSR), bf16 m, fp32 accumulate ----------------
// Batch-8 software pipeline: load 8 (col,val) pairs (tail-clamped, zero-weight),
// then issue all 8 row-gathers before any FMA -> MLP 8 instead of 1.

__global__ void agg_relu(const unsigned short* __restrict__ m, const int* __restrict__ row_ptr,
                         const int* __restrict__ col, const float* __restrict__ val,
                         const float* __restrict__ bias, unsigned short* __restrict__ hidden) {
    int i = blockIdx.x, l = threadIdx.x, c0 = l << 2;
    int p0 = __builtin_amdgcn_readfirstlane(row_ptr[i]);
    int p1 = __builtin_amdgcn_readfirstlane(row_ptr[i + 1]);
    float a0 = 0.f, a1 = 0.f, a2 = 0.f, a3 = 0.f;
    for (int p = p0; p < p1; p += 8) {
        int sj[8]; float wj[8];
#pragma unroll
        for (int j = 0; j < 8; ++j) {
            int q = p + j;
            bool ok = q < p1; if (!ok) q = p1 - 1;   // every row has >=1 edge (self-loop)
            sj[j] = col[q];
            wj[j] = ok ? val[q] : 0.f;
        }
        ushort4 u[8];
#pragma unroll
        for (int j = 0; j < 8; ++j)
            u[j] = *(const ushort4*)(m + (size_t)sj[j] * HID_F + c0);
#pragma unroll
        for (int j = 0; j < 8; ++j) {
            a0 = fmaf(bf2f(u[j].x), wj[j], a0);
            a1 = fmaf(bf2f(u[j].y), wj[j], a1);
            a2 = fmaf(bf2f(u[j].z), wj[j], a2);
            a3 = fmaf(bf2f(u[j].w), wj[j], a3);
        }
    }
    float4 b = *(const float4*)(bias + c0);
    a0 = fmaxf(a0 + b.x, 0.f); a1 = fmaxf(a1 + b.y, 0.f);
    a2 = fmaxf(a2 + b.z, 0.f); a3 = fmaxf(a3 + b.w, 0.f);
    ushort4 o = make_ushort4(f2bf(a0), f2bf(a1), f2bf(a2), f2bf(a3));
    *(ushort4*)(hidden + (size_t)i * HID_F + c0) = o;
}

__global__ void agg_out(const unsigned short* __restrict__ m, const int* __restrict__ row_ptr,
                        const int* __restrict__ col, const float* __restrict__ val,
                        const float* __restrict__ bmu, const float* __restrict__ blv,
                        float* __restrict__ out, int N) {
    int i = blockIdx.x, l = threadIdx.x, c0 = l << 2;
    int p0 = __builtin_amdgcn_readfirstlane(row_ptr[i]);
    int p1 = __builtin_amdgcn_readfirstlane(row_ptr[i + 1]);
    float a0 = 0.f, a1 = 0.f, a2 = 0.f, a3 = 0.f;
    for (int p = p0; p < p1; p += 8) {
        int sj[8]; float wj[8];
#pragma unroll
        for (int j = 0; j < 8; ++j) {
            int q = p + j;
            bool ok = q < p1; if (!ok) q = p1 - 1;
            sj[j] = col[q];
            wj[j] = ok ? val[q] : 0.f;
        }
        ushort4 u[8];
#pragma unroll
        for (int j = 0; j < 8; ++j)
            u[j] = *(const ushort4*)(m + (size_t)sj[j] * HID_F + c0);
#pragma unroll
        for (int j = 0; j < 8; ++j) {
            a0 = fmaf(bf2f(u[j].x), wj[j], a0);
            a1 = fmaf(bf2f(u[j].y), wj[j], a1);
            a2 = fmaf(bf2f(u[j].z), wj[j], a2);
            a3 = fmaf(bf2f(u[j].w), wj[j], a3);
        }
    }
    if (l < 32) {
        float4 b = *(const float4*)(bmu + c0);
        float4 o = make_float4(a0 + b.x, a1 + b.y, a2 + b.z, a3 + b.w);
        *(float4*)(out + (size_t)i * LAT_F + c0) = o;
    } else {
        int c = c0 - 128;
        float4 b = *(const float4*)(blv + c);
        float4 o = make_float4(a0 + b.x, a1 + b.y, a2 + b.z, a3 + b.w);
        *(float4*)(out + (size_t)(N + i) * LAT_F + c) = o;
    }
}

// ---------------- launch ----------------

extern "C" void kernel_launch(void* const* d_in, const int* in_sizes, int n_in,
                              void* d_out, int out_size, void* d_ws, size_t ws_size,
                              hipStream_t stream) {
    const float* x    = (const float*)d_in[0];
    const int*   ei   = (const int*)d_in[1];
    const float* attr = (const float*)d_in[2];
    const float* W1   = (const float*)d_in[3];
    const float* b1   = (const float*)d_in[4];
    const float* Wmu  = (const float*)d_in[5];
    const float* bmu  = (const float*)d_in[6];
    const float* Wlv  = (const float*)d_in[7];
    const float* blv  = (const float*)d_in[8];
    float* out = (float*)d_out;

    const int N  = in_sizes[0] / IN_F;   // 50000
    const int E  = in_sizes[2];          // 800000
    const int EN = E + N;

    char* w = (char*)d_ws;
    size_t off = 0;
    auto carve = [&](size_t bytes) -> void* {
        void* p = w + off; off += (bytes + 255) & ~(size_t)255; return p;
    };
    unsigned long long* packed = (unsigned long long*)carve((size_t)N * 8);
    float*          dis       = (float*)carve((size_t)N * 4);
    int*            row_ptr   = (int*)  carve((size_t)(N + 1) * 4);
    int*            blockSums = (int*)  carve(64 * 4);
    int*            slot      = (int*)  carve((size_t)E * 4);
    int*            col       = (int*)  carve((size_t)EN * 4);
    float*          val       = (float*)carve((size_t)EN * 4);
    unsigned short* Bf1       = (unsigned short*)carve((size_t)HID_F * IN_F * 2);
    unsigned short* Bf2       = (unsigned short*)carve((size_t)HID_F * HID_F * 2);
    unsigned short* m         = (unsigned short*)carve((size_t)N * HID_F * 2);  // m1, reused as m2
    unsigned short* hidden    = (unsigned short*)carve((size_t)N * HID_F * 2);

    prep_all<<<(HID_F * IN_F + 255) / 256, 256, 0, stream>>>(W1, Wmu, Wlv, packed, Bf1, Bf2, N);

    edge_deg<<<(E + 255) / 256, 256, 0, stream>>>(ei, attr, packed, slot, E);

    int NB = (N + 1023) / 1024;
    scan_blocks<<<NB, 256, 0, stream>>>(packed, dis, row_ptr, blockSums, N);
    scan_sums<<<1, 64, 0, stream>>>(blockSums, NB);
    scan_add<<<NB, 256, 0, stream>>>(row_ptr, blockSums, N, EN);

    fill_csr<<<(EN + 255) / 256, 256, 0, stream>>>(ei, attr, slot, dis, row_ptr, col, val, E, N);

    int ntiles = (N + 63) / 64;
    // m1 = bf16(x) @ W1   [50000,512]x[512,256] -> bf16
    gemm_breg<false, IN_F><<<256, 512, 0, stream>>>(x, Bf1, m, N, ntiles);
    // hidden = relu(A_hat * m1 + b1) -> bf16
    agg_relu<<<N, 64, 0, stream>>>(m, row_ptr, col, val, b1, hidden);
    // m2 = hidden @ [W_mu | W_lv]   [50000,256]x[256,256] -> bf16
    gemm_breg<true, HID_F><<<256, 512, 0, stream>>>(hidden, Bf2, m, N, ntiles);
    // (mu|logvar) = A_hat * m2 + (b_mu|b_lv) -> fp32 d_out
    agg_out<<<N, 64, 0, stream>>>(m, row_ptr, col, val, bmu, blv, out, N);
}

// Round 4
// 401.863 us; speedup vs baseline: 1.0893x; 1.0034x over previous
//
#include <hip/hip_runtime.h>

#define IN_F 512
#define HID_F 256
#define LAT_F 128

typedef __bf16 bf16x8 __attribute__((ext_vector_type(8)));
typedef float floatx4 __attribute__((ext_vector_type(4)));

#define FIX_SCALE 1048576.0f   // 2^20 fixed-point for degree accumulation

__device__ __forceinline__ unsigned short f2bf(float f) {
    union { float f; unsigned u; } v; v.f = f;
    unsigned r = (v.u + 0x7fff + ((v.u >> 16) & 1)) >> 16;
    return (unsigned short)r;
}
__device__ __forceinline__ float bf2f(unsigned short h) {
    union { unsigned u; float f; } v; v.u = ((unsigned)h) << 16;
    return v.f;
}

// ---------------- fused prep: packed init + B in MFMA-fragment order ----------------
// Bf layout: frag f = ((wave*NKS + ks)*2 + jj), element (lane, j):
//   Bf[(f*64 + lane)*8 + j] = W[k][n],  n = wave*32 + jj*16 + (lane&15),
//                                        k = ks*32 + (lane>>4)*8 + j

__global__ void prep_all(const float* __restrict__ W1, const float* __restrict__ Wmu,
                         const float* __restrict__ Wlv, unsigned long long* __restrict__ packed,
                         unsigned short* __restrict__ Bf1, unsigned short* __restrict__ Bf2,
                         int N) {
    int t = blockIdx.x * 256 + threadIdx.x;
    if (t < N) packed[t] = (1ULL << 32) | (unsigned long long)(unsigned)FIX_SCALE;  // count=1, w=1.0
    if (t < HID_F * IN_F) {            // GEMM1 frags: 8 waves x 16 ks x 2 jj x 64 lanes x 8
        int j = t & 7, l = (t >> 3) & 63, jj = (t >> 9) & 1, ks = (t >> 10) & 15, w = t >> 14;
        int n = w * 32 + jj * 16 + (l & 15);
        int k = ks * 32 + (l >> 4) * 8 + j;
        Bf1[t] = f2bf(W1[(size_t)k * HID_F + n]);
    }
    if (t < HID_F * HID_F) {           // GEMM2 frags: 8 waves x 8 ks x 2 jj x 64 lanes x 8
        int j = t & 7, l = (t >> 3) & 63, jj = (t >> 9) & 1, ks = (t >> 10) & 7, w = t >> 13;
        int n = w * 32 + jj * 16 + (l & 15);
        int k = ks * 32 + (l >> 4) * 8 + j;
        float v = (n < 128) ? Wmu[(size_t)k * LAT_F + n] : Wlv[(size_t)k * LAT_F + (n - 128)];
        Bf2[t] = f2bf(v);
    }
}

// ---------------- degree pass: ONE u64 atomic per edge; returns CSR slot ----------------

__global__ void edge_deg(const int* __restrict__ ei, const float* __restrict__ attr,
                         unsigned long long* __restrict__ packed, int* __restrict__ slot, int E) {
    int e = blockIdx.x * 256 + threadIdx.x;
    if (e < E) {
        int d = ei[E + e];
        unsigned fw = __float2uint_rn(attr[e] * FIX_SCALE);
        unsigned long long old = atomicAdd(&packed[d], (1ULL << 32) | (unsigned long long)fw);
        slot[e] = (int)(old >> 32);    // count before increment (self-loop holds slot 0)
    }
}

// ---------------- scan pass 1 (fused with dis computation) ----------------

__global__ void scan_blocks(const unsigned long long* __restrict__ packed,
                            float* __restrict__ dis, int* __restrict__ excl,
                            int* __restrict__ blockSums, int N) {
    __shared__ int sdata[256];
    int tid = threadIdx.x;
    int base = blockIdx.x * 1024 + tid * 4;
    int v[4]; int sum = 0;
#pragma unroll
    for (int j = 0; j < 4; ++j) {
        int c = 0;
        if (base + j < N) {
            unsigned long long p = packed[base + j];
            c = (int)(p >> 32);
            float dg = (float)(unsigned)(p & 0xffffffffu) * (1.0f / FIX_SCALE);
            dis[base + j] = dg > 0.f ? rsqrtf(fmaxf(dg, 1e-12f)) : 0.f;
        }
        v[j] = c; sum += c;
    }
    sdata[tid] = sum;
    __syncthreads();
    for (int off = 1; off < 256; off <<= 1) {
        int t = (tid >= off) ? sdata[tid - off] : 0;
        __syncthreads();
        sdata[tid] += t;
        __syncthreads();
    }
    if (tid == 255) blockSums[blockIdx.x] = sdata[255];
    int run = sdata[tid] - sum;
#pragma unroll
    for (int j = 0; j < 4; ++j) { if (base + j < N) excl[base + j] = run; run += v[j]; }
}

__global__ void scan_sums(int* blockSums, int NB) {
    __shared__ int s[64];
    int tid = threadIdx.x;
    int v = (tid < NB) ? blockSums[tid] : 0;
    s[tid] = v;
    __syncthreads();
    for (int off = 1; off < 64; off <<= 1) {
        int t = (tid >= off) ? s[tid - off] : 0;
        __syncthreads();
        s[tid] += t;
        __syncthreads();
    }
    if (tid < NB) blockSums[tid] = s[tid] - v;
}

__global__ void scan_add(int* row_ptr, const int* __restrict__ blockSums, int N, int total) {
    int tid = threadIdx.x;
    int base = blockIdx.x * 1024 + tid * 4;
    int add = blockSums[blockIdx.x];
#pragma unroll
    for (int j = 0; j < 4; ++j) if (base + j < N) row_ptr[base + j] += add;
    if (blockIdx.x == 0 && tid == 0) row_ptr[N] = total;
}

// ---------------- CSR fill (NO atomics — slots precomputed) ----------------

__global__ void fill_csr(const int* __restrict__ ei, const float* __restrict__ attr,
                         const int* __restrict__ slot, const float* __restrict__ dis,
                         const int* __restrict__ row_ptr,
                         int* __restrict__ col, float* __restrict__ val, int E, int N) {
    int e = blockIdx.x * 256 + threadIdx.x;
    if (e >= E + N) return;
    int s, d, sl; float w;
    if (e < E) { s = ei[e]; d = ei[E + e]; w = attr[e]; sl = slot[e]; }
    else       { s = d = e - E; w = 1.0f; sl = 0; }
    int pos = row_ptr[d] + sl;
    col[pos] = s;
    val[pos] = dis[s] * w * dis[d];
}

// ---------------- B-in-registers MFMA GEMM (unchanged from round 3) ----------------

template <bool ABF16, int KK>
__global__ __launch_bounds__(512, 2) void gemm_breg(const void* __restrict__ Avoid,
                                                    const unsigned short* __restrict__ Bfrag,
                                                    unsigned short* __restrict__ C,
                                                    int M, int ntiles) {
    constexpr int NKS = KK / 32;      // total 32-k MFMA steps (16 / 8)
    constexpr int S   = KK / 128;     // super-steps per tile (4 / 2)
    __shared__ unsigned short As[2][64 * 128];   // 2 x 16KB

    int tid = threadIdx.x;
    int wave = tid >> 6, lane = tid & 63;
    int mrow = lane & 15, quad = lane >> 4;

    const unsigned short* Abf = (const unsigned short*)Avoid;
    const float*          Afp = (const float*)Avoid;

    bf16x8 bfr[NKS][2];
#pragma unroll
    for (int ks = 0; ks < NKS; ++ks)
#pragma unroll
        for (int jj = 0; jj < 2; ++jj)
            bfr[ks][jj] = *(const bf16x8*)(Bfrag +
                ((((size_t)wave * NKS + ks) * 2 + jj) * 64 + lane) * 8);

    int c  = tid & 15;                 // 16B chunk within 128-k slab
    int r0 = tid >> 4;                 // 0..31
    int cs0 = (c ^ (r0 & 7)) << 3;            // swizzled ushort offset, row r0
    int cs1 = (c ^ ((r0 + 32) & 7)) << 3;     // swizzled ushort offset, row r0+32

    float4 a0, a1, a2, a3;
    uint4  u0, u1;

    auto issue = [&](int t_, int s_) {
        int g0 = t_ * 64 + r0;       if (g0 >= M) g0 = M - 1;
        int g1 = t_ * 64 + r0 + 32;  if (g1 >= M) g1 = M - 1;
        if constexpr (ABF16) {
            u0 = *(const uint4*)(Abf + (size_t)g0 * KK + s_ * 128 + c * 8);
            u1 = *(const uint4*)(Abf + (size_t)g1 * KK + s_ * 128 + c * 8);
        } else {
            const float* p0 = Afp + (size_t)g0 * KK + s_ * 128 + c * 8;
            const float* p1 = Afp + (size_t)g1 * KK + s_ * 128 + c * 8;
            a0 = *(const float4*)p0; a1 = *(const float4*)(p0 + 4);
            a2 = *(const float4*)p1; a3 = *(const float4*)(p1 + 4);
        }
    };

    floatx4 acc[4][2];
#pragma unroll
    for (int i = 0; i < 4; ++i)
#pragma unroll
        for (int jj = 0; jj < 2; ++jj) acc[i][jj] = (floatx4){0.f, 0.f, 0.f, 0.f};

    int tile = blockIdx.x;
    if (tile < ntiles) issue(tile, 0);
    int cur = 0;

    for (; tile < ntiles; tile += gridDim.x) {
#pragma unroll
        for (int s = 0; s < S; ++s) {
            if constexpr (ABF16) {
                *(uint4*)&As[cur][r0 * 128 + cs0] = u0;
                *(uint4*)&As[cur][(r0 + 32) * 128 + cs1] = u1;
            } else {
                unsigned short h0[8] = {f2bf(a0.x), f2bf(a0.y), f2bf(a0.z), f2bf(a0.w),
                                        f2bf(a1.x), f2bf(a1.y), f2bf(a1.z), f2bf(a1.w)};
                unsigned short h1[8] = {f2bf(a2.x), f2bf(a2.y), f2bf(a2.z), f2bf(a2.w),
                                        f2bf(a3.x), f2bf(a3.y), f2bf(a3.z), f2bf(a3.w)};
                *(uint4*)&As[cur][r0 * 128 + cs0] = *(uint4*)h0;
                *(uint4*)&As[cur][(r0 + 32) * 128 + cs1] = *(uint4*)h1;
            }
            if (s + 1 < S) issue(tile, s + 1);
            else if (tile + (int)gridDim.x < ntiles) issue(tile + gridDim.x, 0);

            asm volatile("s_waitcnt lgkmcnt(0)" ::: "memory");
            __builtin_amdgcn_s_barrier();

#pragma unroll
            for (int ks = 0; ks < 4; ++ks) {
#pragma unroll
                for (int i = 0; i < 4; ++i) {
                    int row = i * 16 + mrow;
                    bf16x8 af = *(const bf16x8*)&As[cur][row * 128 +
                                    (((ks * 4 + quad) ^ (row & 7)) << 3)];
#pragma unroll
                    for (int jj = 0; jj < 2; ++jj)
                        acc[i][jj] = __builtin_amdgcn_mfma_f32_16x16x32_bf16(
                            af, bfr[s * 4 + ks][jj], acc[i][jj], 0, 0, 0);
                }
            }
            asm volatile("s_waitcnt lgkmcnt(0)" ::: "memory");
            __builtin_amdgcn_s_barrier();
            cur ^= 1;
        }
#pragma unroll
        for (int i = 0; i < 4; ++i)
#pragma unroll
            for (int jj = 0; jj < 2; ++jj) {
                int colo = wave * 32 + jj * 16 + mrow;
#pragma unroll
                for (int v = 0; v < 4; ++v) {
                    int row = tile * 64 + i * 16 + quad * 4 + v;
                    if (row < M) C[(size_t)row * HID_F + colo] = f2bf(acc[i][jj][v]);
                }
                acc[i][jj] = (floatx4){0.f, 0.f, 0.f, 0.f};
            }
    }
}

// ---------------- aggregation (gather, CSR), bf16 m, fp32 accumulate ----------------
// Batch-16 software pipeline: load 16 (col,val) pairs (tail-clamped, zero-weight),
// then issue all 16 row-gathers before any FMA -> MLP 16.

__global__ void agg_relu(const unsigned short* __restrict__ m, const int* __restrict__ row_ptr,
                         const int* __restrict__ col, const float* __restrict__ val,
                         const float* __restrict__ bias, unsigned short* __restrict__ hidden) {
    int i = blockIdx.x, l = threadIdx.x, c0 = l << 2;
    int p0 = __builtin_amdgcn_readfirstlane(row_ptr[i]);
    int p1 = __builtin_amdgcn_readfirstlane(row_ptr[i + 1]);
    float a0 = 0.f, a1 = 0.f, a2 = 0.f, a3 = 0.f;
    for (int p = p0; p < p1; p += 16) {
        int sj[16]; float wj[16];
#pragma unroll
        for (int j = 0; j < 16; ++j) {
            int q = p + j;
            bool ok = q < p1; if (!ok) q = p1 - 1;   // every row has >=1 edge (self-loop)
            sj[j] = col[q];
            wj[j] = ok ? val[q] : 0.f;
        }
        ushort4 u[16];
#pragma unroll
        for (int j = 0; j < 16; ++j)
            u[j] = *(const ushort4*)(m + (size_t)sj[j] * HID_F + c0);
#pragma unroll
        for (int j = 0; j < 16; ++j) {
            a0 = fmaf(bf2f(u[j].x), wj[j], a0);
            a1 = fmaf(bf2f(u[j].y), wj[j], a1);
            a2 = fmaf(bf2f(u[j].z), wj[j], a2);
            a3 = fmaf(bf2f(u[j].w), wj[j], a3);
        }
    }
    float4 b = *(const float4*)(bias + c0);
    a0 = fmaxf(a0 + b.x, 0.f); a1 = fmaxf(a1 + b.y, 0.f);
    a2 = fmaxf(a2 + b.z, 0.f); a3 = fmaxf(a3 + b.w, 0.f);
    ushort4 o = make_ushort4(f2bf(a0), f2bf(a1), f2bf(a2), f2bf(a3));
    *(ushort4*)(hidden + (size_t)i * HID_F + c0) = o;
}

__global__ void agg_out(const unsigned short* __restrict__ m, const int* __restrict__ row_ptr,
                        const int* __restrict__ col, const float* __restrict__ val,
                        const float* __restrict__ bmu, const float* __restrict__ blv,
                        float* __restrict__ out, int N) {
    int i = blockIdx.x, l = threadIdx.x, c0 = l << 2;
    int p0 = __builtin_amdgcn_readfirstlane(row_ptr[i]);
    int p1 = __builtin_amdgcn_readfirstlane(row_ptr[i + 1]);
    float a0 = 0.f, a1 = 0.f, a2 = 0.f, a3 = 0.f;
    for (int p = p0; p < p1; p += 16) {
        int sj[16]; float wj[16];
#pragma unroll
        for (int j = 0; j < 16; ++j) {
            int q = p + j;
            bool ok = q < p1; if (!ok) q = p1 - 1;
            sj[j] = col[q];
            wj[j] = ok ? val[q] : 0.f;
        }
        ushort4 u[16];
#pragma unroll
        for (int j = 0; j < 16; ++j)
            u[j] = *(const ushort4*)(m + (size_t)sj[j] * HID_F + c0);
#pragma unroll
        for (int j = 0; j < 16; ++j) {
            a0 = fmaf(bf2f(u[j].x), wj[j], a0);
            a1 = fmaf(bf2f(u[j].y), wj[j], a1);
            a2 = fmaf(bf2f(u[j].z), wj[j], a2);
            a3 = fmaf(bf2f(u[j].w), wj[j], a3);
        }
    }
    if (l < 32) {
        float4 b = *(const float4*)(bmu + c0);
        float4 o = make_float4(a0 + b.x, a1 + b.y, a2 + b.z, a3 + b.w);
        *(float4*)(out + (size_t)i * LAT_F + c0) = o;
    } else {
        int c = c0 - 128;
        float4 b = *(const float4*)(blv + c);
        float4 o = make_float4(a0 + b.x, a1 + b.y, a2 + b.z, a3 + b.w);
        *(float4*)(out + (size_t)(N + i) * LAT_F + c) = o;
    }
}

// ---------------- launch ----------------

extern "C" void kernel_launch(void* const* d_in, const int* in_sizes, int n_in,
                              void* d_out, int out_size, void* d_ws, size_t ws_size,
                              hipStream_t stream) {
    const float* x    = (const float*)d_in[0];
    const int*   ei   = (const int*)d_in[1];
    const float* attr = (const float*)d_in[2];
    const float* W1   = (const float*)d_in[3];
    const float* b1   = (const float*)d_in[4];
    const float* Wmu  = (const float*)d_in[5];
    const float* bmu  = (const float*)d_in[6];
    const float* Wlv  = (const float*)d_in[7];
    const float* blv  = (const float*)d_in[8];
    float* out = (float*)d_out;

    const int N  = in_sizes[0] / IN_F;   // 50000
    const int E  = in_sizes[2];          // 800000
    const int EN = E + N;

    char* w = (char*)d_ws;
    size_t off = 0;
    auto carve = [&](size_t bytes) -> void* {
        void* p = w + off; off += (bytes + 255) & ~(size_t)255; return p;
    };
    unsigned long long* packed = (unsigned long long*)carve((size_t)N * 8);
    float*          dis       = (float*)carve((size_t)N * 4);
    int*            row_ptr   = (int*)  carve((size_t)(N + 1) * 4);
    int*            blockSums = (int*)  carve(64 * 4);
    int*            slot      = (int*)  carve((size_t)E * 4);
    int*            col       = (int*)  carve((size_t)EN * 4);
    float*          val       = (float*)carve((size_t)EN * 4);
    unsigned short* Bf1       = (unsigned short*)carve((size_t)HID_F * IN_F * 2);
    unsigned short* Bf2       = (unsigned short*)carve((size_t)HID_F * HID_F * 2);
    unsigned short* m         = (unsigned short*)carve((size_t)N * HID_F * 2);  // m1, reused as m2
    unsigned short* hidden    = (unsigned short*)carve((size_t)N * HID_F * 2);

    prep_all<<<(HID_F * IN_F + 255) / 256, 256, 0, stream>>>(W1, Wmu, Wlv, packed, Bf1, Bf2, N);

    edge_deg<<<(E + 255) / 256, 256, 0, stream>>>(ei, attr, packed, slot, E);

    int NB = (N + 1023) / 1024;
    scan_blocks<<<NB, 256, 0, stream>>>(packed, dis, row_ptr, blockSums, N);
    scan_sums<<<1, 64, 0, stream>>>(blockSums, NB);
    scan_add<<<NB, 256, 0, stream>>>(row_ptr, blockSums, N, EN);

    fill_csr<<<(EN + 255) / 256, 256, 0, stream>>>(ei, attr, slot, dis, row_ptr, col, val, E, N);

    int ntiles = (N + 63) / 64;
    // m1 = bf16(x) @ W1   [50000,512]x[512,256] -> bf16
    gemm_breg<false, IN_F><<<256, 512, 0, stream>>>(x, Bf1, m, N, ntiles);
    // hidden = relu(A_hat * m1 + b1) -> bf16
    agg_relu<<<N, 64, 0, stream>>>(m, row_ptr, col, val, b1, hidden);
    // m2 = hidden @ [W_mu | W_lv]   [50000,256]x[256,256] -> bf16
    gemm_breg<true, HID_F><<<256, 512, 0, stream>>>(hidden, Bf2, m, N, ntiles);
    // (mu|logvar) = A_hat * m2 + (b_mu|b_lv) -> fp32 d_out
    agg_out<<<N, 64, 0, stream>>>(m, row_ptr, col, val, bmu, blv, out, N);
}